// Round 8
// baseline (5412.793 us; speedup 1.0000x reference)
//
#include <hip/hip_runtime.h>

// Problem constants (from setup_inputs: B=16, N=16384, D=128, S=N/4)
#define BATCH    16
#define NPTS     16384
#define NSAMP    4096
#define NTHREADS 1024
#define PPT      16
#define NWAVE    16

// DPP move helper (disabled lanes keep old value = own value)
template<int CTRL, int RM>
__device__ __forceinline__ float dpp_movf(float v) {
    return __int_as_float(__builtin_amdgcn_update_dpp(
        __float_as_int(v), __float_as_int(v), CTRL, RM, 0xF, false));
}

__device__ __forceinline__ float wave_max64(float v) {
    v = fmaxf(v, dpp_movf<0x111, 0xF>(v));   // row_shr:1
    v = fmaxf(v, dpp_movf<0x112, 0xF>(v));   // row_shr:2
    v = fmaxf(v, dpp_movf<0x114, 0xF>(v));   // row_shr:4
    v = fmaxf(v, dpp_movf<0x118, 0xF>(v));   // row_shr:8
    v = fmaxf(v, dpp_movf<0x142, 0xA>(v));   // row_bcast:15
    v = fmaxf(v, dpp_movf<0x143, 0xC>(v));   // row_bcast:31 -> lane 63 = max
    return v;
}
__device__ __forceinline__ float wave_min64(float v) {
    v = fminf(v, dpp_movf<0x111, 0xF>(v));
    v = fminf(v, dpp_movf<0x112, 0xF>(v));
    v = fminf(v, dpp_movf<0x114, 0xF>(v));
    v = fminf(v, dpp_movf<0x118, 0xF>(v));
    v = fminf(v, dpp_movf<0x142, 0xA>(v));
    v = fminf(v, dpp_movf<0x143, 0xC>(v));
    return v;
}

// spread 6 bits to every 3rd position (Morton interleave component)
__device__ __forceinline__ unsigned spread6(unsigned v) {
    return (v & 1u) | ((v & 2u) << 2) | ((v & 4u) << 4) |
           ((v & 8u) << 6) | ((v & 16u) << 8) | ((v & 32u) << 10);
}

// -----------------------------------------------------------------------------
// FPS with PER-THREAD exact spatial pruning.
//  - Morton bitonic sort groups points; each thread owns 16 contiguous points
//    (tiny bbox), re-sorted by ORIGINAL index in-register (odd-even network)
//    so within-thread k-order == orig-order (exact first-index tie-break).
//  - Skip test per iteration: thread t is provably unaffected when
//    0.9999*mindist(c,box_t)^2 >= tmax_t (= exact max of its pd). Wave
//    recomputes only if ANY lane fails -> near point-granularity pruning.
//  - Cached per-wave candidate {val, orig, coords} republished from uniforms;
//    winner coords flow through LDS (parallel read + readlane), removing the
//    L2 centroid load from the serial chain.
//  - Exact reference semantics: dist=min(dist,(dx2+dy2)+dz2) fp32 no-FMA,
//    argmax first-original-index (ties handled exactly via rare paths).
// -----------------------------------------------------------------------------
__global__ __launch_bounds__(NTHREADS, 4) void fps_kernel(
    const float* __restrict__ xyz, int* __restrict__ sorted_idx)
{
    __shared__ unsigned s_key[NPTS];                 // 64 KiB
    __shared__ unsigned s_bitmap[NPTS / 32];         // 2 KiB
    __shared__ unsigned long long s_slot[2][NWAVE];  // parity {max_bits, orig}
    __shared__ float s_ccf[2][NWAVE * 3];            // parity candidate coords
    __shared__ float s_bb[NWAVE][6];                 // bbox staging
    __shared__ int s_wt[NWAVE];                      // tail scan totals

    const int tid  = threadIdx.x;
    const int lane = tid & 63;
    const int wid  = tid >> 6;
    const int b    = blockIdx.x;

    if (tid < NPTS / 32) s_bitmap[tid] = 0u;

    const float* xb = xyz + (size_t)b * NPTS * 3;

    // ---- global bbox (for Morton quantization) ----
    float mnx = 1e30f, mny = 1e30f, mnz = 1e30f;
    float mxx = -1e30f, mxy = -1e30f, mxz = -1e30f;
    #pragma unroll
    for (int k = 0; k < PPT; ++k) {
        int i = (tid << 4) + k;
        float x = xb[3 * i], y = xb[3 * i + 1], z = xb[3 * i + 2];
        mnx = fminf(mnx, x); mxx = fmaxf(mxx, x);
        mny = fminf(mny, y); mxy = fmaxf(mxy, y);
        mnz = fminf(mnz, z); mxz = fmaxf(mxz, z);
    }
    mnx = wave_min64(mnx); mxx = wave_max64(mxx);
    mny = wave_min64(mny); mxy = wave_max64(mxy);
    mnz = wave_min64(mnz); mxz = wave_max64(mxz);
    if (lane == 63) {
        s_bb[wid][0] = mnx; s_bb[wid][1] = mny; s_bb[wid][2] = mnz;
        s_bb[wid][3] = mxx; s_bb[wid][4] = mxy; s_bb[wid][5] = mxz;
    }
    __syncthreads();
    float glx = s_bb[0][0], gly = s_bb[0][1], glz = s_bb[0][2];
    float ghx = s_bb[0][3], ghy = s_bb[0][4], ghz = s_bb[0][5];
    for (int w = 1; w < NWAVE; ++w) {
        glx = fminf(glx, s_bb[w][0]); gly = fminf(gly, s_bb[w][1]);
        glz = fminf(glz, s_bb[w][2]);
        ghx = fmaxf(ghx, s_bb[w][3]); ghy = fmaxf(ghy, s_bb[w][4]);
        ghz = fmaxf(ghz, s_bb[w][5]);
    }
    float qsx = 63.999f / fmaxf(ghx - glx, 1e-20f);
    float qsy = 63.999f / fmaxf(ghy - gly, 1e-20f);
    float qsz = 63.999f / fmaxf(ghz - glz, 1e-20f);

    // ---- Morton keys ----
    __syncthreads();
    #pragma unroll
    for (int k = 0; k < PPT; ++k) {
        int i = (tid << 4) + k;
        int qx = min(max((int)((xb[3 * i]     - glx) * qsx), 0), 63);
        int qy = min(max((int)((xb[3 * i + 1] - gly) * qsy), 0), 63);
        int qz = min(max((int)((xb[3 * i + 2] - glz) * qsz), 0), 63);
        unsigned cell = spread6((unsigned)qx) | (spread6((unsigned)qy) << 1) |
                        (spread6((unsigned)qz) << 2);
        s_key[i] = (cell << 14) | (unsigned)i;
    }

    // ---- bitonic sort by Morton key (single sort; no second pass) ----
    for (int k = 2; k <= NPTS; k <<= 1) {
        for (int j = k >> 1; j > 0; j >>= 1) {
            __syncthreads();
            #pragma unroll
            for (int m = 0; m < PPT; ++m) {
                int i = (m << 10) | tid;
                int l = i ^ j;
                if (l > i) {
                    unsigned a = s_key[i], c2 = s_key[l];
                    bool up = ((i & k) == 0);
                    if ((a > c2) == up) { s_key[i] = c2; s_key[l] = a; }
                }
            }
        }
    }
    __syncthreads();

    // ---- per-thread: extract origs, in-register sort ascending (odd-even) ----
    unsigned o[PPT];
    #pragma unroll
    for (int k = 0; k < PPT; ++k) o[k] = s_key[(tid << 4) + k] & 0x3FFFu;
    #pragma unroll
    for (int r = 0; r < 16; ++r) {
        #pragma unroll
        for (int i = (r & 1); i + 1 < PPT; i += 2) {
            unsigned lo = min(o[i], o[i + 1]);
            unsigned hi = max(o[i], o[i + 1]);
            o[i] = lo; o[i + 1] = hi;
        }
    }
    #pragma unroll
    for (int k = 0; k < PPT; ++k) s_key[(tid << 4) + k] = o[k];

    // ---- gather coords; thread bbox; init pd/tmax ----
    float px[PPT], py[PPT], pz[PPT], pd[PPT];
    float bxl = 1e30f, byl = 1e30f, bzl = 1e30f;
    float bxh = -1e30f, byh = -1e30f, bzh = -1e30f;
    #pragma unroll
    for (int k = 0; k < PPT; ++k) {
        int g = (int)o[k];
        px[k] = xb[3 * g]; py[k] = xb[3 * g + 1]; pz[k] = xb[3 * g + 2];
        pd[k] = 1e10f;
        bxl = fminf(bxl, px[k]); bxh = fmaxf(bxh, px[k]);
        byl = fminf(byl, py[k]); byh = fmaxf(byh, py[k]);
        bzl = fminf(bzl, pz[k]); bzh = fmaxf(bzh, pz[k]);
    }
    float tmax = 1e10f;

    // cached per-wave candidate (uniform); published while dirty
    float mval = 1e10f, mcx = 0.f, mcy = 0.f, mcz = 0.f;
    int   morig = 0, dirty = 0;

    float cx = xb[0], cy = xb[1], cz = xb[2];   // initial farthest = index 0
    if (tid == 0) s_bitmap[0] = 1u;
    __syncthreads();

    for (int s = 0; s < NSAMP - 1; ++s) {
        const int p = s & 1;

        // ---- per-thread exact skip test ----
        float tx = fmaxf(fmaxf(__fsub_rn(bxl, cx), __fsub_rn(cx, bxh)), 0.f);
        float ty = fmaxf(fmaxf(__fsub_rn(byl, cy), __fsub_rn(cy, byh)), 0.f);
        float tz = fmaxf(fmaxf(__fsub_rn(bzl, cz), __fsub_rn(cz, bzh)), 0.f);
        float md2 = 0.9999f * __fadd_rn(__fadd_rn(__fmul_rn(tx, tx),
                                                  __fmul_rn(ty, ty)),
                                        __fmul_rn(tz, tz));
        bool need = (md2 < tmax);

        if (__ballot(need) != 0ull) {      // wave-uniform: recompute whole wave
            float bv = -1.0f;
            int   bk = 0;
            #pragma unroll
            for (int k = 0; k < PPT; ++k) {
                float dx = __fsub_rn(px[k], cx);
                float dy = __fsub_rn(py[k], cy);
                float dz = __fsub_rn(pz[k], cz);
                float d  = __fadd_rn(__fadd_rn(__fmul_rn(dx, dx),
                                               __fmul_rn(dy, dy)),
                                     __fmul_rn(dz, dz));
                float nd = fminf(pd[k], d);
                pd[k] = nd;
                if (nd > bv) { bv = nd; bk = k; }  // strict >: min orig (k sorted)
            }
            tmax = bv;
            int bo_mine = (int)s_key[(tid << 4) + bk];  // overlapped LDS lookup

            float wv = wave_max64(bv);
            int   mb = __builtin_amdgcn_readlane(__float_as_int(wv), 63);
            float mw = __int_as_float(mb);
            unsigned long long mk = __ballot(bv == mw);
            int sl, bo;
            if (__popcll(mk) == 1) {                   // unique max lane
                sl = __ffsll(mk) - 1;
                bo = __builtin_amdgcn_readlane(bo_mine, sl);
            } else {                                   // rare: min orig over ties
                unsigned long long t = mk;
                bo = 0x7FFFFFFF; sl = 0;
                while (t) {
                    int l = __ffsll(t) - 1; t &= t - 1;
                    int b2 = __builtin_amdgcn_readlane(bo_mine, l);
                    if (b2 < bo) { bo = b2; sl = l; }
                }
            }
            // candidate coords: every lane extracts its own, take lane sl's
            float ax = px[0], ay = py[0], az = pz[0];
            #pragma unroll
            for (int k = 1; k < PPT; ++k)
                if (bk == k) { ax = px[k]; ay = py[k]; az = pz[k]; }
            mcx = __int_as_float(__builtin_amdgcn_readlane(__float_as_int(ax), sl));
            mcy = __int_as_float(__builtin_amdgcn_readlane(__float_as_int(ay), sl));
            mcz = __int_as_float(__builtin_amdgcn_readlane(__float_as_int(az), sl));
            mval = mw; morig = bo; dirty = 2;
        }

        if (dirty > 0) {                   // publish cached candidate (both parities)
            if (lane == 0) {
                s_slot[p][wid] =
                    ((unsigned long long)(unsigned)__float_as_int(mval) << 32) |
                    (unsigned)morig;
                s_ccf[p][wid * 3 + 0] = mcx;
                s_ccf[p][wid * 3 + 1] = mcy;
                s_ccf[p][wid * 3 + 2] = mcz;
            }
            dirty -= 1;
        }

        __syncthreads();   // the ONLY barrier per iteration

        // ---- block winner over 16 wave slots; coords read in parallel ----
        unsigned long long key = s_slot[p][lane & 15];
        float cf = s_ccf[p][lane < 48 ? lane : 0];
        float cv = __int_as_float((int)(key >> 32));
        int   ci = (int)(unsigned)key;
        float rv = cv;
        rv = fmaxf(rv, dpp_movf<0x111, 0xF>(rv));
        rv = fmaxf(rv, dpp_movf<0x112, 0xF>(rv));
        rv = fmaxf(rv, dpp_movf<0x114, 0xF>(rv));
        rv = fmaxf(rv, dpp_movf<0x118, 0xF>(rv));  // lane 15 of row = max
        int   gmb = __builtin_amdgcn_readlane(__float_as_int(rv), 15);
        float gm  = __int_as_float(gmb);
        unsigned long long m2 = __ballot(cv == gm);
        int w, g;
        if (__popcll(m2) == 4) {                   // unique winning wave
            w = __ffsll(m2) - 1;
            g = __builtin_amdgcn_readlane(ci, w);
        } else {                                   // rare: min orig across waves
            unsigned long long t = m2 & 0xFFFFull;
            g = 0x7FFFFFFF; w = 0;
            while (t) {
                int l = __ffsll(t) - 1; t &= t - 1;
                int g2 = __builtin_amdgcn_readlane(ci, l);
                if (g2 < g) { g = g2; w = l; }
            }
        }
        cx = __int_as_float(__builtin_amdgcn_readlane(__float_as_int(cf), w * 3 + 0));
        cy = __int_as_float(__builtin_amdgcn_readlane(__float_as_int(cf), w * 3 + 1));
        cz = __int_as_float(__builtin_amdgcn_readlane(__float_as_int(cf), w * 3 + 2));

        if (tid == 0) s_bitmap[g >> 5] |= (1u << (g & 31));
    }
    __syncthreads();

    // ---- tail: bitmap -> ascending index list via block prefix scan ----
    const int nwords = NPTS / 32;   // 512
    unsigned word = (tid < nwords) ? s_bitmap[tid] : 0u;
    int cnt = __popc(word);
    int inc = cnt;
    #pragma unroll
    for (int off = 1; off < 64; off <<= 1) {
        int n = __shfl_up(inc, off);
        if (lane >= off) inc += n;
    }
    if (lane == 63) s_wt[wid] = inc;
    __syncthreads();
    int base = inc - cnt;
    for (int w = 0; w < wid; ++w) base += s_wt[w];
    int* sb = sorted_idx + (size_t)b * NSAMP;
    int pos = base;
    unsigned wmask = word;
    while (wmask) {
        int k = __ffs(wmask) - 1;
        wmask &= wmask - 1;
        sb[pos++] = tid * 32 + k;
    }
}

// -----------------------------------------------------------------------------
// Gather kernel: one wave per sampled row.
//   out0 = new_xyz [B,S,3]; out1 = concat(xyz, points) [B,S,1,131]; out2 [B,S,128]
// -----------------------------------------------------------------------------
__global__ void gather_kernel(
    const float* __restrict__ xyz, const float* __restrict__ points,
    const float* __restrict__ pres, const int* __restrict__ sorted_idx,
    float* __restrict__ out0, float* __restrict__ out1, float* __restrict__ out2)
{
    int gw   = (int)((blockIdx.x * (unsigned)blockDim.x + threadIdx.x) >> 6);
    int lane = threadIdx.x & 63;
    if (gw >= BATCH * NSAMP) return;
    int b = gw >> 12;               // NSAMP == 4096
    int i = sorted_idx[gw];

    const float* xs = xyz    + ((size_t)b * NPTS + i) * 3;
    const float* ps = points + ((size_t)b * NPTS + i) * 128;
    const float* rs = pres   + ((size_t)b * NPTS + i) * 128;

    if (lane < 3) out0[(size_t)gw * 3 + lane] = xs[lane];

    float* o1 = out1 + (size_t)gw * 131;
    #pragma unroll
    for (int j = 0; j < 3; ++j) {
        int c = lane + 64 * j;
        if (c < 131) o1[c] = (c < 3) ? xs[c] : ps[c - 3];
    }

    const float2* r2 = (const float2*)rs;
    float2* o2 = (float2*)(out2 + (size_t)gw * 128);
    o2[lane] = r2[lane];
}

extern "C" void kernel_launch(void* const* d_in, const int* in_sizes, int n_in,
                              void* d_out, int out_size, void* d_ws, size_t ws_size,
                              hipStream_t stream)
{
    const float* xyz    = (const float*)d_in[0];
    const float* points = (const float*)d_in[1];
    const float* pres   = (const float*)d_in[2];

    float* out  = (float*)d_out;
    float* out0 = out;                                     // B*S*3
    float* out1 = out0 + (size_t)BATCH * NSAMP * 3;        // B*S*131
    float* out2 = out1 + (size_t)BATCH * NSAMP * 131;      // B*S*128

    int* sorted = (int*)d_ws;   // B*S ints = 256 KiB scratch

    fps_kernel<<<BATCH, NTHREADS, 0, stream>>>(xyz, sorted);

    int total_threads = BATCH * NSAMP * 64;   // one wave per sampled row
    int threads = 256;
    int blocks  = total_threads / threads;
    gather_kernel<<<blocks, threads, 0, stream>>>(xyz, points, pres, sorted,
                                                  out0, out1, out2);
}

// Round 9
// 4816.006 us; speedup vs baseline: 1.1239x; 1.1239x over previous
//
#include <hip/hip_runtime.h>

// Problem constants (from setup_inputs: B=16, N=16384, D=128, S=N/4)
#define BATCH    16
#define NPTS     16384
#define NSAMP    4096
#define NTHREADS 1024
#define PPT      16
#define NWAVE    16

// DPP move helper (disabled lanes keep old value = own value)
template<int CTRL, int RM>
__device__ __forceinline__ float dpp_movf(float v) {
    return __int_as_float(__builtin_amdgcn_update_dpp(
        __float_as_int(v), __float_as_int(v), CTRL, RM, 0xF, false));
}

__device__ __forceinline__ float wave_max64(float v) {
    v = fmaxf(v, dpp_movf<0x111, 0xF>(v));   // row_shr:1
    v = fmaxf(v, dpp_movf<0x112, 0xF>(v));   // row_shr:2
    v = fmaxf(v, dpp_movf<0x114, 0xF>(v));   // row_shr:4
    v = fmaxf(v, dpp_movf<0x118, 0xF>(v));   // row_shr:8
    v = fmaxf(v, dpp_movf<0x142, 0xA>(v));   // row_bcast:15
    v = fmaxf(v, dpp_movf<0x143, 0xC>(v));   // row_bcast:31 -> lane 63 = max
    return v;
}

// order-preserving float -> uint map (IEEE total order)
__device__ __forceinline__ unsigned xform(float f) {
    unsigned u = __float_as_uint(f);
    return (u & 0x80000000u) ? ~u : (u | 0x80000000u);
}

// (segmented) bitonic sort of s_key in LDS; segbound = segment size (pow2).
// Segments are segbound-aligned; i^j stays in-segment for j < segbound.
__device__ __forceinline__ void bitonic_lds(unsigned* s_key, int tid, int segbound) {
    for (int k = 2; k <= segbound; k <<= 1) {
        for (int j = k >> 1; j > 0; j >>= 1) {
            __syncthreads();
            #pragma unroll
            for (int m = 0; m < PPT; ++m) {
                int i = (m << 10) | tid;
                int l = i ^ j;
                if (l > i) {
                    unsigned a = s_key[i], c2 = s_key[l];
                    bool up = ((i & k) == 0);
                    if ((a > c2) == up) { s_key[i] = c2; s_key[l] = a; }
                }
            }
        }
    }
}

// -----------------------------------------------------------------------------
// FPS with per-thread exact pruning over a BALANCED RANK-SPLIT GRID.
//  - 3 sorts build the partition: x -> 8 slabs(2048); y within slab -> 64
//    columns(256); z within column -> 1024 cells of 16 points. Every cell is
//    a tight disjoint box (rank splits nest -> NO Morton straddle, the
//    failure mode of rounds 7-8 where VALUBusy showed ~all waves recomputing).
//  - Thread t owns cell t: 16 points (orig-sorted in-register), tight bbox,
//    cached exact tmax = max of its pd. Skip lane when
//    0.9999*mindist(c,box)^2 >= tmax (fp-exact proof: fl-monotone per step,
//    same add association as reference, 0.9999 guard).
//  - Exact reference semantics: dist=min(dist,(dx2+dy2)+dz2) fp32 no-FMA,
//    argmax first-original-index (rare tie paths exact).
// -----------------------------------------------------------------------------
__global__ __launch_bounds__(NTHREADS, 4) void fps_kernel(
    const float* __restrict__ xyz, int* __restrict__ sorted_idx)
{
    __shared__ unsigned s_key[NPTS];                 // 64 KiB
    __shared__ unsigned s_bitmap[NPTS / 32];         // 2 KiB
    __shared__ unsigned long long s_slot[2][NWAVE];  // parity {max_bits, orig}
    __shared__ float s_ccf[2][NWAVE * 3];            // parity candidate coords
    __shared__ int s_wt[NWAVE];                      // tail scan totals

    const int tid  = threadIdx.x;
    const int lane = tid & 63;
    const int wid  = tid >> 6;
    const int b    = blockIdx.x;

    if (tid < NPTS / 32) s_bitmap[tid] = 0u;

    const float* xb = xyz + (size_t)b * NPTS * 3;

    // ---- partition sort 1: by x (full 16384) ----
    #pragma unroll
    for (int k = 0; k < PPT; ++k) {
        int i = (tid << 4) + k;
        s_key[i] = (xform(xb[3 * i]) & 0xFFFFC000u) | (unsigned)i;
    }
    bitonic_lds(s_key, tid, NPTS);
    __syncthreads();

    // ---- sort 2: by y within 8 x-slabs of 2048 ----
    #pragma unroll
    for (int m = 0; m < PPT; ++m) {
        int p = (m << 10) | tid;
        unsigned orig = s_key[p] & 0x3FFFu;
        s_key[p] = (xform(xb[3 * orig + 1]) & 0xFFFFC000u) | orig;
    }
    bitonic_lds(s_key, tid, 2048);
    __syncthreads();

    // ---- sort 3: by z within 64 columns of 256 ----
    #pragma unroll
    for (int m = 0; m < PPT; ++m) {
        int p = (m << 10) | tid;
        unsigned orig = s_key[p] & 0x3FFFu;
        s_key[p] = (xform(xb[3 * orig + 2]) & 0xFFFFC000u) | orig;
    }
    bitonic_lds(s_key, tid, 256);
    __syncthreads();

    // ---- per-thread cell: extract origs, in-register sort ascending ----
    unsigned o[PPT];
    #pragma unroll
    for (int k = 0; k < PPT; ++k) o[k] = s_key[(tid << 4) + k] & 0x3FFFu;
    #pragma unroll
    for (int r = 0; r < 16; ++r) {
        #pragma unroll
        for (int i = (r & 1); i + 1 < PPT; i += 2) {
            unsigned lo = min(o[i], o[i + 1]);
            unsigned hi = max(o[i], o[i + 1]);
            o[i] = lo; o[i + 1] = hi;
        }
    }
    #pragma unroll
    for (int k = 0; k < PPT; ++k) s_key[(tid << 4) + k] = o[k];

    // ---- gather coords; tight cell bbox; init pd/tmax ----
    float px[PPT], py[PPT], pz[PPT], pd[PPT];
    float bxl = 1e30f, byl = 1e30f, bzl = 1e30f;
    float bxh = -1e30f, byh = -1e30f, bzh = -1e30f;
    #pragma unroll
    for (int k = 0; k < PPT; ++k) {
        int g = (int)o[k];
        px[k] = xb[3 * g]; py[k] = xb[3 * g + 1]; pz[k] = xb[3 * g + 2];
        pd[k] = 1e10f;
        bxl = fminf(bxl, px[k]); bxh = fmaxf(bxh, px[k]);
        byl = fminf(byl, py[k]); byh = fmaxf(byh, py[k]);
        bzl = fminf(bzl, pz[k]); bzh = fmaxf(bzh, pz[k]);
    }
    float tmax = 1e10f;

    // cached per-wave candidate (uniform); published while dirty
    float mval = 1e10f, mcx = 0.f, mcy = 0.f, mcz = 0.f;
    int   morig = 0, dirty = 0;

    float cx = xb[0], cy = xb[1], cz = xb[2];   // initial farthest = index 0
    if (tid == 0) s_bitmap[0] = 1u;
    __syncthreads();

    for (int s = 0; s < NSAMP - 1; ++s) {
        const int p = s & 1;

        // ---- per-thread exact skip test (tight cell box) ----
        float tx = fmaxf(fmaxf(__fsub_rn(bxl, cx), __fsub_rn(cx, bxh)), 0.f);
        float ty = fmaxf(fmaxf(__fsub_rn(byl, cy), __fsub_rn(cy, byh)), 0.f);
        float tz = fmaxf(fmaxf(__fsub_rn(bzl, cz), __fsub_rn(cz, bzh)), 0.f);
        float md2 = 0.9999f * __fadd_rn(__fadd_rn(__fmul_rn(tx, tx),
                                                  __fmul_rn(ty, ty)),
                                        __fmul_rn(tz, tz));
        bool need = (md2 < tmax);

        if (__ballot(need) != 0ull) {      // wave-uniform: recompute whole wave
            float bv = -1.0f;
            int   bk = 0;
            #pragma unroll
            for (int k = 0; k < PPT; ++k) {
                float dx = __fsub_rn(px[k], cx);
                float dy = __fsub_rn(py[k], cy);
                float dz = __fsub_rn(pz[k], cz);
                float d  = __fadd_rn(__fadd_rn(__fmul_rn(dx, dx),
                                               __fmul_rn(dy, dy)),
                                     __fmul_rn(dz, dz));
                float nd = fminf(pd[k], d);
                pd[k] = nd;
                if (nd > bv) { bv = nd; bk = k; }  // strict >: min orig (k sorted)
            }
            tmax = bv;
            int bo_mine = (int)s_key[(tid << 4) + bk];

            float wv = wave_max64(bv);
            int   mb = __builtin_amdgcn_readlane(__float_as_int(wv), 63);
            float mw = __int_as_float(mb);
            unsigned long long mk = __ballot(bv == mw);
            int sl, bo;
            if (__popcll(mk) == 1) {                   // unique max lane
                sl = __ffsll(mk) - 1;
                bo = __builtin_amdgcn_readlane(bo_mine, sl);
            } else {                                   // rare: min orig over ties
                unsigned long long t = mk;
                bo = 0x7FFFFFFF; sl = 0;
                while (t) {
                    int l = __ffsll(t) - 1; t &= t - 1;
                    int b2 = __builtin_amdgcn_readlane(bo_mine, l);
                    if (b2 < bo) { bo = b2; sl = l; }
                }
            }
            // candidate coords: every lane extracts its own, take lane sl's
            float ax = px[0], ay = py[0], az = pz[0];
            #pragma unroll
            for (int k = 1; k < PPT; ++k)
                if (bk == k) { ax = px[k]; ay = py[k]; az = pz[k]; }
            mcx = __int_as_float(__builtin_amdgcn_readlane(__float_as_int(ax), sl));
            mcy = __int_as_float(__builtin_amdgcn_readlane(__float_as_int(ay), sl));
            mcz = __int_as_float(__builtin_amdgcn_readlane(__float_as_int(az), sl));
            mval = mw; morig = bo; dirty = 2;
        }

        if (dirty > 0) {                   // publish cached candidate (both parities)
            if (lane == 0) {
                s_slot[p][wid] =
                    ((unsigned long long)(unsigned)__float_as_int(mval) << 32) |
                    (unsigned)morig;
                s_ccf[p][wid * 3 + 0] = mcx;
                s_ccf[p][wid * 3 + 1] = mcy;
                s_ccf[p][wid * 3 + 2] = mcz;
            }
            dirty -= 1;
        }

        __syncthreads();   // the ONLY barrier per iteration

        // ---- block winner over 16 wave slots; coords read in parallel ----
        unsigned long long key = s_slot[p][lane & 15];
        float cf = s_ccf[p][lane < 48 ? lane : 0];
        float cv = __int_as_float((int)(key >> 32));
        int   ci = (int)(unsigned)key;
        float rv = cv;
        rv = fmaxf(rv, dpp_movf<0x111, 0xF>(rv));
        rv = fmaxf(rv, dpp_movf<0x112, 0xF>(rv));
        rv = fmaxf(rv, dpp_movf<0x114, 0xF>(rv));
        rv = fmaxf(rv, dpp_movf<0x118, 0xF>(rv));  // lane 15 of row = max
        int   gmb = __builtin_amdgcn_readlane(__float_as_int(rv), 15);
        float gm  = __int_as_float(gmb);
        unsigned long long m2 = __ballot(cv == gm);
        int w, g;
        if (__popcll(m2) == 4) {                   // unique winning wave
            w = __ffsll(m2) - 1;
            g = __builtin_amdgcn_readlane(ci, w);
        } else {                                   // rare: min orig across waves
            unsigned long long t = m2 & 0xFFFFull;
            g = 0x7FFFFFFF; w = 0;
            while (t) {
                int l = __ffsll(t) - 1; t &= t - 1;
                int g2 = __builtin_amdgcn_readlane(ci, l);
                if (g2 < g) { g = g2; w = l; }
            }
        }
        cx = __int_as_float(__builtin_amdgcn_readlane(__float_as_int(cf), w * 3 + 0));
        cy = __int_as_float(__builtin_amdgcn_readlane(__float_as_int(cf), w * 3 + 1));
        cz = __int_as_float(__builtin_amdgcn_readlane(__float_as_int(cf), w * 3 + 2));

        if (tid == 0) s_bitmap[g >> 5] |= (1u << (g & 31));
    }
    __syncthreads();

    // ---- tail: bitmap -> ascending index list via block prefix scan ----
    const int nwords = NPTS / 32;   // 512
    unsigned word = (tid < nwords) ? s_bitmap[tid] : 0u;
    int cnt = __popc(word);
    int inc = cnt;
    #pragma unroll
    for (int off = 1; off < 64; off <<= 1) {
        int n = __shfl_up(inc, off);
        if (lane >= off) inc += n;
    }
    if (lane == 63) s_wt[wid] = inc;
    __syncthreads();
    int base = inc - cnt;
    for (int w = 0; w < wid; ++w) base += s_wt[w];
    int* sb = sorted_idx + (size_t)b * NSAMP;
    int pos = base;
    unsigned wmask = word;
    while (wmask) {
        int k = __ffs(wmask) - 1;
        wmask &= wmask - 1;
        sb[pos++] = tid * 32 + k;
    }
}

// -----------------------------------------------------------------------------
// Gather kernel: one wave per sampled row.
//   out0 = new_xyz [B,S,3]; out1 = concat(xyz, points) [B,S,1,131]; out2 [B,S,128]
// -----------------------------------------------------------------------------
__global__ void gather_kernel(
    const float* __restrict__ xyz, const float* __restrict__ points,
    const float* __restrict__ pres, const int* __restrict__ sorted_idx,
    float* __restrict__ out0, float* __restrict__ out1, float* __restrict__ out2)
{
    int gw   = (int)((blockIdx.x * (unsigned)blockDim.x + threadIdx.x) >> 6);
    int lane = threadIdx.x & 63;
    if (gw >= BATCH * NSAMP) return;
    int b = gw >> 12;               // NSAMP == 4096
    int i = sorted_idx[gw];

    const float* xs = xyz    + ((size_t)b * NPTS + i) * 3;
    const float* ps = points + ((size_t)b * NPTS + i) * 128;
    const float* rs = pres   + ((size_t)b * NPTS + i) * 128;

    if (lane < 3) out0[(size_t)gw * 3 + lane] = xs[lane];

    float* o1 = out1 + (size_t)gw * 131;
    #pragma unroll
    for (int j = 0; j < 3; ++j) {
        int c = lane + 64 * j;
        if (c < 131) o1[c] = (c < 3) ? xs[c] : ps[c - 3];
    }

    const float2* r2 = (const float2*)rs;
    float2* o2 = (float2*)(out2 + (size_t)gw * 128);
    o2[lane] = r2[lane];
}

extern "C" void kernel_launch(void* const* d_in, const int* in_sizes, int n_in,
                              void* d_out, int out_size, void* d_ws, size_t ws_size,
                              hipStream_t stream)
{
    const float* xyz    = (const float*)d_in[0];
    const float* points = (const float*)d_in[1];
    const float* pres   = (const float*)d_in[2];

    float* out  = (float*)d_out;
    float* out0 = out;                                     // B*S*3
    float* out1 = out0 + (size_t)BATCH * NSAMP * 3;        // B*S*131
    float* out2 = out1 + (size_t)BATCH * NSAMP * 131;      // B*S*128

    int* sorted = (int*)d_ws;   // B*S ints = 256 KiB scratch

    fps_kernel<<<BATCH, NTHREADS, 0, stream>>>(xyz, sorted);

    int total_threads = BATCH * NSAMP * 64;   // one wave per sampled row
    int threads = 256;
    int blocks  = total_threads / threads;
    gather_kernel<<<blocks, threads, 0, stream>>>(xyz, points, pres, sorted,
                                                  out0, out1, out2);
}